// Round 5
// baseline (984.785 us; speedup 1.0000x reference)
//
#include <hip/hip_runtime.h>
#include <hip/hip_bf16.h>

#define UDIM    256
#define ODIM    128
#define ZDIM    1024
#define NSTEPS  48
#define BM      16
#define THREADS 1024
#define NBLOCKS 256   // 4096 / BM

// ws layout in ushort elements — FP16 bits:
//   KR: [0,       393216)   64 tiles x 12 kc x 64 lanes x 8
//   D : [393216,  425984)   8 tiles x 8 kc x 64 lanes x 8
#define KR_FRAGS 393216
#define D_FRAGS  32768

// sA cols: [0,128)=x, [128,384)=h buf0, [384,640)=h buf1, pad to 664 (16B rows)
#define SA_W 664

typedef _Float16 f16x8 __attribute__((ext_vector_type(8)));
typedef float    f32x4 __attribute__((ext_vector_type(4)));

__device__ __forceinline__ ushort f2h_bits(float v) {
    _Float16 h = (_Float16)v;          // v_cvt_f16_f32, RNE
    return *reinterpret_cast<ushort*>(&h);
}
__device__ __forceinline__ float sigmoid_f(float x) {
    return 1.0f / (1.0f + __expf(-x));
}
__device__ __forceinline__ float tanh_f(float x) {
    return 1.0f - 2.0f / (__expf(2.0f * x) + 1.0f);
}

// ---- prep: pack weights into MFMA B-fragment order, fp16 (round-nearest) ----
__global__ void prep_weights(const float* __restrict__ kernel_w,   // [128,1024]
                             const float* __restrict__ rec_w,      // [256,1024]
                             const float* __restrict__ dense_w,    // [256,128]
                             ushort* __restrict__ ws) {
    int idx = blockIdx.x * blockDim.x + threadIdx.x;
    if (idx < KR_FRAGS) {
        int j  = idx & 7;
        int l  = (idx >> 3) & 63;
        int fc = idx >> 9;          // n*12 + kc
        int kc = fc % 12;
        int n  = fc / 12;
        int k   = kc * 32 + (l >> 4) * 8 + j;
        int col = n * 16 + (l & 15);
        float wv = (k < 128) ? kernel_w[k * ZDIM + col]
                             : rec_w[(k - 128) * ZDIM + col];
        ws[idx] = f2h_bits(wv);
    } else if (idx < KR_FRAGS + D_FRAGS) {
        int e  = idx - KR_FRAGS;
        int j  = e & 7;
        int l  = (e >> 3) & 63;
        int kc = (e >> 9) & 7;
        int n  = e >> 12;
        int k   = kc * 32 + (l >> 4) * 8 + j;
        int col = n * 16 + (l & 15);
        ws[KR_FRAGS + e] = f2h_bits(dense_w[k * ODIM + col]);
    }
}

// B-buffer load: 4 n-tiles (g=0..3) of one kc into NAMED registers.
// Named scalars (not arrays) make prefetch hoisting WAR-bounded: a load into
// bX cannot move above the MFMA that reads bX. This is the structural fix for
// the round-4 register balloon / scratch-spill blowup.
#define LOADB4(B0, B1, B2, B3, KC)                                              \
    B0 = *reinterpret_cast<const f16x8*>(krbase + (size_t)(KC) * 512);          \
    B1 = *reinterpret_cast<const f16x8*>(krbase +  98304 + (size_t)(KC) * 512); \
    B2 = *reinterpret_cast<const f16x8*>(krbase + 196608 + (size_t)(KC) * 512); \
    B3 = *reinterpret_cast<const f16x8*>(krbase + 294912 + (size_t)(KC) * 512);

#define MFMA4(B0, B1, B2, B3, KC)                                               \
    {                                                                           \
        const int koff_ = ((KC) < 4) ? ((KC) * 32 + rg * 8)                     \
                                     : (hrd + ((KC) - 4) * 32 + rg * 8);        \
        f16x8 a_ = *reinterpret_cast<const f16x8*>(&sA[cl][koff_]);             \
        acc[0] = __builtin_amdgcn_mfma_f32_16x16x32_f16(a_, B0, acc[0], 0, 0, 0); \
        acc[1] = __builtin_amdgcn_mfma_f32_16x16x32_f16(a_, B1, acc[1], 0, 0, 0); \
        acc[2] = __builtin_amdgcn_mfma_f32_16x16x32_f16(a_, B2, acc[2], 0, 0, 0); \
        acc[3] = __builtin_amdgcn_mfma_f32_16x16x32_f16(a_, B3, acc[3], 0, 0, 0); \
    }

// ---- main: BM=16 persistent LSTM, fp16 single-pass, depth-2 B prefetch ----
__global__ __launch_bounds__(THREADS, 4) void lstm_mfma_kernel(
    const float* __restrict__ last_input,  // [4096,128]
    const float* __restrict__ h0,          // [4096,256]
    const float* __restrict__ c0,          // [4096,256]
    const float* __restrict__ bias,        // [1024]
    const float* __restrict__ dense_b,     // [128]
    const ushort* __restrict__ wsro,
    float* __restrict__ out)               // [4096,48,128]
{
    const ushort* KR = wsro;

    __shared__ ushort sA[BM][SA_W];                  // fp16 bits
    __shared__ __align__(16) ushort sDw[D_FRAGS];    // dense weights, fp16 bits

    const int t  = threadIdx.x;
    const int w  = t >> 6;          // wave 0..15
    const int l  = t & 63;
    const int cl = l & 15;          // A row within tile / C col
    const int rg = l >> 4;          // C rows 4*rg..+4, k-group
    const int blockRow = blockIdx.x * BM;

    // ---- stage dense weights into LDS (once) ----
    for (int i = t * 8; i < D_FRAGS; i += THREADS * 8)
        *reinterpret_cast<f16x8*>(&sDw[i]) =
            *reinterpret_cast<const f16x8*>(&wsro[KR_FRAGS + i]);

    // ---- stage x0 (cols 0..127) and h0 (buf1: cols 384..639) ----
    for (int i = t; i < BM * ODIM; i += THREADS) {
        int r = i >> 7, c = i & 127;
        sA[r][c] = f2h_bits(last_input[(blockRow + r) * ODIM + c]);
    }
    for (int i = t; i < BM * UDIM; i += THREADS) {
        int r = i >> 8, c = i & 255;
        sA[r][384 + c] = f2h_bits(h0[(blockRow + r) * UDIM + c]);
    }

    // ---- per-lane state: units u = 16*w + cl, rows 4*rg + r ----
    const int unit = 16 * w + cl;
    float cstate[4];
    #pragma unroll
    for (int r = 0; r < 4; ++r)
        cstate[r] = c0[(blockRow + 4 * rg + r) * UDIM + unit];

    float bz[4];
    #pragma unroll
    for (int g = 0; g < 4; ++g)
        bz[g] = bias[256 * g + unit];
    const float db = dense_b[16 * (w & 7) + cl];

    // per-lane KR base (ushort elements); per-(g,kc) offsets fold into addressing
    const ushort* krbase = KR + (size_t)w * 6144 + (size_t)l * 8;

    // ---- prime the two B buffers with kc0, kc1 ----
    f16x8 bA0, bA1, bA2, bA3;
    f16x8 bB0, bB1, bB2, bB3;
    LOADB4(bA0, bA1, bA2, bA3, 0)
    LOADB4(bB0, bB1, bB2, bB3, 1)

    __syncthreads();

    for (int s = 0; s < NSTEPS; ++s) {
        const int pw  = s & 1;
        const int hrd = 128 + (pw ^ 1) * 256;   // h read base (prev step)
        const int hwr = 128 + pw * 256;         // h write base (this step)

        // ======== GEMM1: Z[16,1024] = A[16,384] @ KR + bias ========
        // Schedule: use(kc) then load(kc+2) into the just-freed buffer.
        // Final two bodies prefetch NEXT STEP's kc0/kc1 (weights step-invariant),
        // so the stream keeps issuing across gates/dense/barriers.
        f32x4 acc[4];
        #pragma unroll
        for (int g = 0; g < 4; ++g)
            acc[g] = (f32x4){bz[g], bz[g], bz[g], bz[g]};

        MFMA4(bA0, bA1, bA2, bA3, 0)   LOADB4(bA0, bA1, bA2, bA3, 2)
        MFMA4(bB0, bB1, bB2, bB3, 1)   LOADB4(bB0, bB1, bB2, bB3, 3)
        MFMA4(bA0, bA1, bA2, bA3, 2)   LOADB4(bA0, bA1, bA2, bA3, 4)
        MFMA4(bB0, bB1, bB2, bB3, 3)   LOADB4(bB0, bB1, bB2, bB3, 5)
        MFMA4(bA0, bA1, bA2, bA3, 4)   LOADB4(bA0, bA1, bA2, bA3, 6)
        MFMA4(bB0, bB1, bB2, bB3, 5)   LOADB4(bB0, bB1, bB2, bB3, 7)
        MFMA4(bA0, bA1, bA2, bA3, 6)   LOADB4(bA0, bA1, bA2, bA3, 8)
        MFMA4(bB0, bB1, bB2, bB3, 7)   LOADB4(bB0, bB1, bB2, bB3, 9)
        MFMA4(bA0, bA1, bA2, bA3, 8)   LOADB4(bA0, bA1, bA2, bA3, 10)
        MFMA4(bB0, bB1, bB2, bB3, 9)   LOADB4(bB0, bB1, bB2, bB3, 11)
        MFMA4(bA0, bA1, bA2, bA3, 10)  LOADB4(bA0, bA1, bA2, bA3, 0)
        MFMA4(bB0, bB1, bB2, bB3, 11)  LOADB4(bB0, bB1, bB2, bB3, 1)

        // ======== gates + state update; h_new into the OTHER buffer ========
        // No barrier needed before these writes: buffer hwr was last read in
        // GEMM1(s-1); every wave has passed the end-of-step barrier since.
        #pragma unroll
        for (int r = 0; r < 4; ++r) {
            float iv = sigmoid_f(acc[0][r]);
            float fv = sigmoid_f(acc[1][r]);
            float gv = tanh_f(acc[2][r]);
            float ov = sigmoid_f(acc[3][r]);
            float cn = fv * cstate[r] + iv * gv;
            cstate[r] = cn;
            float hv = ov * tanh_f(cn);
            sA[4 * rg + r][hwr + unit] = f2h_bits(hv);
        }
        __syncthreads();   // B2: h_new visible; also orders GEMM1 x-reads vs y-write

        // ======== dense: Y[16,128] = H[16,256] @ Wd + bd, relu (waves 0..7) ========
        if (w < 8) {
            f32x4 dacc = (f32x4){db, db, db, db};
            #pragma unroll
            for (int kc = 0; kc < 8; ++kc) {
                const int koff = hwr + kc * 32 + rg * 8;
                f16x8 ah = *reinterpret_cast<const f16x8*>(&sA[cl][koff]);
                f16x8 b  = *reinterpret_cast<const f16x8*>(&sDw[w * 4096 + kc * 512 + l * 8]);
                dacc = __builtin_amdgcn_mfma_f32_16x16x32_f16(ah, b, dacc, 0, 0, 0);
            }
            #pragma unroll
            for (int r = 0; r < 4; ++r) {
                float y = fmaxf(dacc[r], 0.0f);
                int row = 4 * rg + r;
                out[((size_t)(blockRow + row) * NSTEPS + s) * ODIM + 16 * w + cl] = y;
                sA[row][16 * w + cl] = f2h_bits(y);
            }
        }
        __syncthreads();   // B4: next-step x ready
    }
}

extern "C" void kernel_launch(void* const* d_in, const int* in_sizes, int n_in,
                              void* d_out, int out_size, void* d_ws, size_t ws_size,
                              hipStream_t stream) {
    const float* last_input = (const float*)d_in[0];
    const float* h0         = (const float*)d_in[1];
    const float* c0         = (const float*)d_in[2];
    const float* kernel_w   = (const float*)d_in[3];
    const float* rec_w      = (const float*)d_in[4];
    const float* bias       = (const float*)d_in[5];
    const float* dense_w    = (const float*)d_in[6];
    const float* dense_b    = (const float*)d_in[7];
    float* out  = (float*)d_out;
    ushort* ws  = (ushort*)d_ws;

    const int prep_total = KR_FRAGS + D_FRAGS;
    hipLaunchKernelGGL(prep_weights, dim3((prep_total + 255) / 256), dim3(256), 0, stream,
                       kernel_w, rec_w, dense_w, ws);
    hipLaunchKernelGGL(lstm_mfma_kernel, dim3(NBLOCKS), dim3(THREADS), 0, stream,
                       last_input, h0, c0, bias, dense_b, (const ushort*)ws, out);
}

// Round 6
// 420.796 us; speedup vs baseline: 2.3403x; 2.3403x over previous
//
#include <hip/hip_runtime.h>
#include <hip/hip_bf16.h>

#define UDIM    256
#define ODIM    128
#define ZDIM    1024
#define NSTEPS  48
#define BM      16
#define THREADS 1024
#define NBLOCKS 256   // 4096 / BM

// ws layout in ushort elements — FP16 bits (11-bit mantissa; strictly more
// accurate than the original bf16-hi weights at the same byte count):
//   KR: [0,       393216)   64 tiles x 12 kc x 64 lanes x 8
//   D : [393216,  425984)   8 tiles x 8 kc x 64 lanes x 8
#define KR_FRAGS 393216
#define D_FRAGS  32768

// sA cols: [0,128)=x, [128,384)=h; pad to 392 (784B rows, 16B aligned) — the
// round-0 geometry, verified clean. Bank conflicts are from the b16 write
// scatter (stride-invariant, measured), not these reads.
#define SA_W 392

typedef _Float16 f16x8 __attribute__((ext_vector_type(8)));
typedef float    f32x4 __attribute__((ext_vector_type(4)));

__device__ __forceinline__ ushort f2h_bits(float v) {
    _Float16 h = (_Float16)v;          // v_cvt_f16_f32, RNE
    return *reinterpret_cast<ushort*>(&h);
}
__device__ __forceinline__ float sigmoid_f(float x) {
    return 1.0f / (1.0f + __expf(-x));
}
__device__ __forceinline__ float tanh_f(float x) {
    return 1.0f - 2.0f / (__expf(2.0f * x) + 1.0f);
}

// ---- prep: pack weights into MFMA B-fragment order, fp16 (round-nearest) ----
__global__ void prep_weights(const float* __restrict__ kernel_w,   // [128,1024]
                             const float* __restrict__ rec_w,      // [256,1024]
                             const float* __restrict__ dense_w,    // [256,128]
                             ushort* __restrict__ ws) {
    int idx = blockIdx.x * blockDim.x + threadIdx.x;
    if (idx < KR_FRAGS) {
        int j  = idx & 7;
        int l  = (idx >> 3) & 63;
        int fc = idx >> 9;          // n*12 + kc
        int kc = fc % 12;
        int n  = fc / 12;
        int k   = kc * 32 + (l >> 4) * 8 + j;
        int col = n * 16 + (l & 15);
        float wv = (k < 128) ? kernel_w[k * ZDIM + col]
                             : rec_w[(k - 128) * ZDIM + col];
        ws[idx] = f2h_bits(wv);
    } else if (idx < KR_FRAGS + D_FRAGS) {
        int e  = idx - KR_FRAGS;
        int j  = e & 7;
        int l  = (e >> 3) & 63;
        int kc = (e >> 9) & 7;
        int n  = e >> 12;
        int k   = kc * 32 + (l >> 4) * 8 + j;
        int col = n * 16 + (l & 15);
        ws[KR_FRAGS + e] = f2h_bits(dense_w[k * ODIM + col]);
    }
}

// ---- main: round-0 skeleton, fp16 single-pass MFMA ----
// Load structure FROZEN per r4/r5 post-mortem: inline B-loads inside a
// runtime-indexed `#pragma unroll 4` loop. No register prefetch (SSA renaming
// defeats any source-level bound and spills to scratch — measured 3.3 GB).
__global__ __launch_bounds__(THREADS, 4) void lstm_mfma_kernel(
    const float* __restrict__ last_input,  // [4096,128]
    const float* __restrict__ h0,          // [4096,256]
    const float* __restrict__ c0,          // [4096,256]
    const float* __restrict__ bias,        // [1024]
    const float* __restrict__ dense_b,     // [128]
    const ushort* __restrict__ wsro,
    float* __restrict__ out)               // [4096,48,128]
{
    const ushort* KR = wsro;

    __shared__ ushort sA[BM][SA_W];                  // fp16 bits
    __shared__ __align__(16) ushort sDw[D_FRAGS];    // dense weights, fp16 bits

    const int t  = threadIdx.x;
    const int w  = t >> 6;          // wave 0..15
    const int l  = t & 63;
    const int cl = l & 15;          // A row within tile / C col
    const int rg = l >> 4;          // C rows 4*rg..+4, k-group
    const int blockRow = blockIdx.x * BM;

    // ---- stage dense weights into LDS (once) ----
    for (int i = t * 8; i < D_FRAGS; i += THREADS * 8)
        *reinterpret_cast<f16x8*>(&sDw[i]) =
            *reinterpret_cast<const f16x8*>(&wsro[KR_FRAGS + i]);

    // ---- stage x0 (cols 0..127) and h0 (cols 128..383) ----
    for (int i = t; i < BM * ODIM; i += THREADS) {
        int r = i >> 7, c = i & 127;
        sA[r][c] = f2h_bits(last_input[(blockRow + r) * ODIM + c]);
    }
    for (int i = t; i < BM * UDIM; i += THREADS) {
        int r = i >> 8, c = i & 255;
        sA[r][128 + c] = f2h_bits(h0[(blockRow + r) * UDIM + c]);
    }

    // ---- per-lane state: wave w owns units u = 16*w + cl, rows 4*rg..+4 ----
    const int unit = 16 * w + cl;
    float cstate[4];
    #pragma unroll
    for (int r = 0; r < 4; ++r)
        cstate[r] = c0[(blockRow + 4 * rg + r) * UDIM + unit];

    float bz[4];
    #pragma unroll
    for (int g = 0; g < 4; ++g)
        bz[g] = bias[256 * g + unit];
    const float db = dense_b[16 * (w & 7) + cl];

    __syncthreads();

    for (int s = 0; s < NSTEPS; ++s) {
        // ======== GEMM1: Z[16,1024] = A[16,384] @ KR + bias (single-pass f16) ========
        f32x4 acc[4];
        #pragma unroll
        for (int g = 0; g < 4; ++g)
            acc[g] = (f32x4){bz[g], bz[g], bz[g], bz[g]};

        #pragma unroll 4
        for (int kc = 0; kc < 12; ++kc) {
            const int koff = kc * 32 + rg * 8;
            f16x8 a = *reinterpret_cast<const f16x8*>(&sA[cl][koff]);
            #pragma unroll
            for (int g = 0; g < 4; ++g) {
                const int n = w + 16 * g;
                const int fo = ((n * 12 + kc) * 64 + l) * 8;
                f16x8 b = *reinterpret_cast<const f16x8*>(KR + fo);
                acc[g] = __builtin_amdgcn_mfma_f32_16x16x32_f16(a, b, acc[g], 0, 0, 0);
            }
        }
        __syncthreads();   // B1: all GEMM1 reads of sA (x,h) complete

        // ======== gates + state update (in registers) ========
        #pragma unroll
        for (int r = 0; r < 4; ++r) {
            float iv = sigmoid_f(acc[0][r]);
            float fv = sigmoid_f(acc[1][r]);
            float gv = tanh_f(acc[2][r]);
            float ov = sigmoid_f(acc[3][r]);
            float cn = fv * cstate[r] + iv * gv;
            cstate[r] = cn;
            float hv = ov * tanh_f(cn);
            sA[4 * rg + r][128 + unit] = f2h_bits(hv);
        }
        __syncthreads();   // B2: h_new visible

        // ======== dense: Y[16,128] = H[16,256] @ Wd + bd, relu (waves 0..7) ========
        if (w < 8) {
            f32x4 dacc = (f32x4){db, db, db, db};
            #pragma unroll
            for (int kc = 0; kc < 8; ++kc) {
                const int koff = 128 + kc * 32 + rg * 8;
                f16x8 ah = *reinterpret_cast<const f16x8*>(&sA[cl][koff]);
                f16x8 b  = *reinterpret_cast<const f16x8*>(&sDw[w * 4096 + kc * 512 + l * 8]);
                dacc = __builtin_amdgcn_mfma_f32_16x16x32_f16(ah, b, dacc, 0, 0, 0);
            }
            #pragma unroll
            for (int r = 0; r < 4; ++r) {
                float y = fmaxf(dacc[r], 0.0f);
                int row = 4 * rg + r;
                out[((size_t)(blockRow + row) * NSTEPS + s) * ODIM + 16 * w + cl] = y;
                sA[row][16 * w + cl] = f2h_bits(y);
            }
        }
        __syncthreads();   // B4: next-step x ready
    }
}

extern "C" void kernel_launch(void* const* d_in, const int* in_sizes, int n_in,
                              void* d_out, int out_size, void* d_ws, size_t ws_size,
                              hipStream_t stream) {
    const float* last_input = (const float*)d_in[0];
    const float* h0         = (const float*)d_in[1];
    const float* c0         = (const float*)d_in[2];
    const float* kernel_w   = (const float*)d_in[3];
    const float* rec_w      = (const float*)d_in[4];
    const float* bias       = (const float*)d_in[5];
    const float* dense_w    = (const float*)d_in[6];
    const float* dense_b    = (const float*)d_in[7];
    float* out  = (float*)d_out;
    ushort* ws  = (ushort*)d_ws;

    const int prep_total = KR_FRAGS + D_FRAGS;
    hipLaunchKernelGGL(prep_weights, dim3((prep_total + 255) / 256), dim3(256), 0, stream,
                       kernel_w, rec_w, dense_w, ws);
    hipLaunchKernelGGL(lstm_mfma_kernel, dim3(NBLOCKS), dim3(THREADS), 0, stream,
                       last_input, h0, c0, bias, dense_b, (const ushort*)ws, out);
}

// Round 7
// 361.924 us; speedup vs baseline: 2.7210x; 1.1627x over previous
//
#include <hip/hip_runtime.h>
#include <hip/hip_bf16.h>

#define UDIM    256
#define ODIM    128
#define ZDIM    1024
#define NSTEPS  48
#define BM      16
#define THREADS 1024
#define NBLOCKS 256   // 4096 / BM

// ws layout in ushort elements — FP16 bits:
//   KR: [0,       393216)   64 tiles x 12 kc x 64 lanes x 8
//   D : [393216,  425984)   8 tiles x 8 kc x 64 lanes x 8
#define KR_FRAGS 393216
#define D_FRAGS  32768

// sA cols: [0,128)=x, [128,384)=h buf0, [384,640)=h buf1, pad to 648
// (row = 1296 B, 16B-aligned so ds_read_b128 stays legal).
#define SA_W 648

typedef _Float16 f16x8 __attribute__((ext_vector_type(8)));
typedef float    f32x4 __attribute__((ext_vector_type(4)));

__device__ __forceinline__ ushort f2h_bits(float v) {
    _Float16 h = (_Float16)v;          // v_cvt_f16_f32, RNE
    return *reinterpret_cast<ushort*>(&h);
}
__device__ __forceinline__ float sigmoid_f(float x) {
    return 1.0f / (1.0f + __expf(-x));
}
__device__ __forceinline__ float tanh_f(float x) {
    return 1.0f - 2.0f / (__expf(2.0f * x) + 1.0f);
}

// ---- prep: pack weights into MFMA B-fragment order, fp16 (round-nearest) ----
__global__ void prep_weights(const float* __restrict__ kernel_w,   // [128,1024]
                             const float* __restrict__ rec_w,      // [256,1024]
                             const float* __restrict__ dense_w,    // [256,128]
                             ushort* __restrict__ ws) {
    int idx = blockIdx.x * blockDim.x + threadIdx.x;
    if (idx < KR_FRAGS) {
        int j  = idx & 7;
        int l  = (idx >> 3) & 63;
        int fc = idx >> 9;          // n*12 + kc
        int kc = fc % 12;
        int n  = fc / 12;
        int k   = kc * 32 + (l >> 4) * 8 + j;
        int col = n * 16 + (l & 15);
        float wv = (k < 128) ? kernel_w[k * ZDIM + col]
                             : rec_w[(k - 128) * ZDIM + col];
        ws[idx] = f2h_bits(wv);
    } else if (idx < KR_FRAGS + D_FRAGS) {
        int e  = idx - KR_FRAGS;
        int j  = e & 7;
        int l  = (e >> 3) & 63;
        int kc = (e >> 9) & 7;
        int n  = e >> 12;
        int k   = kc * 32 + (l >> 4) * 8 + j;
        int col = n * 16 + (l & 15);
        ws[KR_FRAGS + e] = f2h_bits(dense_w[k * ODIM + col]);
    }
}

// ---- main: fp16 single-pass, fused-phase schedule (2 barriers/step) ----
// Dependence chain: gates(s) -> {dense(s), GEMM1-h-part(s+1)} ; dense(s) ->
// GEMM1-x-part(s+1). So next step's recurrent half (32 MFMAs, 512 KB stream)
// runs on ALL 16 waves in the same phase as dense (8 waves) — no idle-wave
// dense phase, and the KR stream issues across the whole step.
// Load structure FROZEN per r4/r5: inline loads, runtime kc, unroll<=4.
__global__ __launch_bounds__(THREADS, 4) void lstm_mfma_kernel(
    const float* __restrict__ last_input,  // [4096,128]
    const float* __restrict__ h0,          // [4096,256]
    const float* __restrict__ c0,          // [4096,256]
    const float* __restrict__ bias,        // [1024]
    const float* __restrict__ dense_b,     // [128]
    const ushort* __restrict__ wsro,
    float* __restrict__ out)               // [4096,48,128]
{
    const ushort* KR = wsro;

    __shared__ ushort sA[BM][SA_W];                  // fp16 bits
    __shared__ __align__(16) ushort sDw[D_FRAGS];    // dense weights, fp16 bits

    const int t  = threadIdx.x;
    const int w  = t >> 6;          // wave 0..15
    const int l  = t & 63;
    const int cl = l & 15;          // A row within tile / C col
    const int rg = l >> 4;          // C rows 4*rg..+4, k-group
    const int blockRow = blockIdx.x * BM;

    // ---- stage dense weights into LDS (once) ----
    for (int i = t * 8; i < D_FRAGS; i += THREADS * 8)
        *reinterpret_cast<f16x8*>(&sDw[i]) =
            *reinterpret_cast<const f16x8*>(&wsro[KR_FRAGS + i]);

    // ---- stage x0 (cols 0..127) and h0 (buf1: cols 384..639) ----
    for (int i = t; i < BM * ODIM; i += THREADS) {
        int r = i >> 7, c = i & 127;
        sA[r][c] = f2h_bits(last_input[(blockRow + r) * ODIM + c]);
    }
    for (int i = t; i < BM * UDIM; i += THREADS) {
        int r = i >> 8, c = i & 255;
        sA[r][384 + c] = f2h_bits(h0[(blockRow + r) * UDIM + c]);
    }

    // ---- per-lane state: wave w owns units u = 16*w + cl, rows 4*rg..+4 ----
    const int unit = 16 * w + cl;
    float cstate[4];
    #pragma unroll
    for (int r = 0; r < 4; ++r)
        cstate[r] = c0[(blockRow + 4 * rg + r) * UDIM + unit];

    float bz[4];
    #pragma unroll
    for (int g = 0; g < 4; ++g)
        bz[g] = bias[256 * g + unit];
    const float db = dense_b[16 * (w & 7) + cl];

    __syncthreads();

    // ---- prologue: acc = bias + h-part(h0)  (h0 lives in buf1, base 384) ----
    f32x4 acc[4];
    #pragma unroll
    for (int g = 0; g < 4; ++g)
        acc[g] = (f32x4){bz[g], bz[g], bz[g], bz[g]};

    #pragma unroll 4
    for (int kc = 4; kc < 12; ++kc) {
        const int koff = 384 + (kc - 4) * 32 + rg * 8;
        f16x8 a = *reinterpret_cast<const f16x8*>(&sA[cl][koff]);
        #pragma unroll
        for (int g = 0; g < 4; ++g) {
            const int n = w + 16 * g;
            const int fo = ((n * 12 + kc) * 64 + l) * 8;
            f16x8 b = *reinterpret_cast<const f16x8*>(KR + fo);
            acc[g] = __builtin_amdgcn_mfma_f32_16x16x32_f16(a, b, acc[g], 0, 0, 0);
        }
    }

    for (int s = 0; s < NSTEPS; ++s) {
        const int hb = 128 + 256 * (s & 1);   // h buffer this step's gates write

        // ======== x-part: acc += x(s) @ K  (kc 0..3; x written by dense(s-1)) ========
        #pragma unroll 4
        for (int kc = 0; kc < 4; ++kc) {
            const int koff = kc * 32 + rg * 8;
            f16x8 a = *reinterpret_cast<const f16x8*>(&sA[cl][koff]);
            #pragma unroll
            for (int g = 0; g < 4; ++g) {
                const int n = w + 16 * g;
                const int fo = ((n * 12 + kc) * 64 + l) * 8;
                f16x8 b = *reinterpret_cast<const f16x8*>(KR + fo);
                acc[g] = __builtin_amdgcn_mfma_f32_16x16x32_f16(a, b, acc[g], 0, 0, 0);
            }
        }

        // ======== gates: h_new -> hbuf[s&1] (registers; no barrier needed:
        // hbuf[s&1]'s previous readers finished two barriers ago) ========
        #pragma unroll
        for (int r = 0; r < 4; ++r) {
            float iv = sigmoid_f(acc[0][r]);
            float fv = sigmoid_f(acc[1][r]);
            float gv = tanh_f(acc[2][r]);
            float ov = sigmoid_f(acc[3][r]);
            float cn = fv * cstate[r] + iv * gv;
            cstate[r] = cn;
            float hv = ov * tanh_f(cn);
            sA[4 * rg + r][hb + unit] = f2h_bits(hv);
        }
        __syncthreads();   // B2: h_new visible; also orders x-part reads vs dense y-writes

        // ======== fused phase: next-step h-part (all waves) + dense (w<8) ========
        f32x4 acc2[4];
        #pragma unroll
        for (int g = 0; g < 4; ++g)
            acc2[g] = (f32x4){bz[g], bz[g], bz[g], bz[g]};

        if (s < NSTEPS - 1) {
            #pragma unroll 4
            for (int kc = 4; kc < 12; ++kc) {
                const int koff = hb + (kc - 4) * 32 + rg * 8;
                f16x8 a = *reinterpret_cast<const f16x8*>(&sA[cl][koff]);
                #pragma unroll
                for (int g = 0; g < 4; ++g) {
                    const int n = w + 16 * g;
                    const int fo = ((n * 12 + kc) * 64 + l) * 8;
                    f16x8 b = *reinterpret_cast<const f16x8*>(KR + fo);
                    acc2[g] = __builtin_amdgcn_mfma_f32_16x16x32_f16(a, b, acc2[g], 0, 0, 0);
                }
            }
        }

        if (w < 8) {
            f32x4 dacc = (f32x4){db, db, db, db};
            #pragma unroll
            for (int kc = 0; kc < 8; ++kc) {
                const int koff = hb + kc * 32 + rg * 8;
                f16x8 ah = *reinterpret_cast<const f16x8*>(&sA[cl][koff]);
                f16x8 b  = *reinterpret_cast<const f16x8*>(&sDw[w * 4096 + kc * 512 + l * 8]);
                dacc = __builtin_amdgcn_mfma_f32_16x16x32_f16(ah, b, dacc, 0, 0, 0);
            }
            #pragma unroll
            for (int r = 0; r < 4; ++r) {
                float y = fmaxf(dacc[r], 0.0f);
                int row = 4 * rg + r;
                out[((size_t)(blockRow + row) * NSTEPS + s) * ODIM + 16 * w + cl] = y;
                sA[row][16 * w + cl] = f2h_bits(y);
            }
        }
        __syncthreads();   // B4: y/x(s+1) ready; hbuf reads done before next rewrite

        #pragma unroll
        for (int g = 0; g < 4; ++g)
            acc[g] = acc2[g];
    }
}

extern "C" void kernel_launch(void* const* d_in, const int* in_sizes, int n_in,
                              void* d_out, int out_size, void* d_ws, size_t ws_size,
                              hipStream_t stream) {
    const float* last_input = (const float*)d_in[0];
    const float* h0         = (const float*)d_in[1];
    const float* c0         = (const float*)d_in[2];
    const float* kernel_w   = (const float*)d_in[3];
    const float* rec_w      = (const float*)d_in[4];
    const float* bias       = (const float*)d_in[5];
    const float* dense_w    = (const float*)d_in[6];
    const float* dense_b    = (const float*)d_in[7];
    float* out  = (float*)d_out;
    ushort* ws  = (ushort*)d_ws;

    const int prep_total = KR_FRAGS + D_FRAGS;
    hipLaunchKernelGGL(prep_weights, dim3((prep_total + 255) / 256), dim3(256), 0, stream,
                       kernel_w, rec_w, dense_w, ws);
    hipLaunchKernelGGL(lstm_mfma_kernel, dim3(NBLOCKS), dim3(THREADS), 0, stream,
                       last_input, h0, c0, bias, dense_b, (const ushort*)ws, out);
}